// Round 1
// baseline (2633.598 us; speedup 1.0000x reference)
//
#include <hip/hip_runtime.h>
#include <math.h>

// ---------------- dims / constants ----------------
#define EPS_Q 1e-4
#define TOLC  1e-3

// ws layout: doubles first
#define OFF_D22   0        // [32][32]
#define OFF_RINV  1024     // [32][32]
#define OFF_VR    2048     // [160][32]
#define OFF_T1    7168     // [160][32]
#define OFF_H     12288    // [160][160]
#define OFF_E     37888    // [64][64]
#define OFF_EI    41984    // [64][64]
#define OFF_TMP   46080    // [64][64]
#define OFF_TMP2  50176    // [64][64]
#define D_END     54272    // doubles
// float blob appended after doubles (byte offset D_END*8 = 434176, 16B aligned)
#define F_WX    0          // [64][132]  rows: [A1(64) | A2(32) | A3(32) | pad4]
#define F_WY    8448       // [32][132]  rows: [C2(64) | D21(32) | D22(32) | pad4]
#define F_D11   12672      // [32][32]   strictly-lower, pre-scaled by 1/Lam_i
#define F_WA    13696      // [32][96]   rows: [-H21(64) | D12(32)] * (1/Lam_s)
#define F_LDS_CNT 13696    // floats staged into LDS by main kernel (WX+WY+D11)

// ================= prep 1: D22, R_cal^-1, vec_r, T1 =================
__global__ __launch_bounds__(256, 1) void prep1(
    const float* __restrict__ B2, const float* __restrict__ C2,
    const float* __restrict__ D12, const float* __restrict__ L,
    const float* __restrict__ U, const float* __restrict__ D21,
    const float* __restrict__ gam, double* __restrict__ wsd)
{
  __shared__ double aug[32][65];
  __shared__ double sFac[32];
  __shared__ int sPiv;
  const int tid = threadIdx.x;
  const double g = (double)gam[0];
  double* D22d = wsd + OFF_D22;

  // D22 = (g+1) I + L^T L + (U - U^T)
  for (int idx = tid; idx < 1024; idx += 256) {
    int i = idx >> 5, j = idx & 31;
    double s = (i == j) ? (g + 1.0) : 0.0;
    for (int k = 0; k < 32; ++k) s += (double)L[k*32+i] * (double)L[k*32+j];
    s += (double)U[i*32+j] - (double)U[j*32+i];
    D22d[idx] = s;
  }
  __syncthreads();
  // R_cal = -2g I + D22 + D22^T - eps * D22^T D22  -> aug left; I -> aug right
  for (int idx = tid; idx < 1024; idx += 256) {
    int i = idx >> 5, j = idx & 31;
    double s = (i == j) ? (-2.0 * g) : 0.0;
    s += D22d[i*32+j] + D22d[j*32+i];
    double q = 0.0;
    for (int k = 0; k < 32; ++k) q += D22d[k*32+i] * D22d[k*32+j];
    aug[i][j] = s - EPS_Q * q;
    aug[i][32+j] = (i == j) ? 1.0 : 0.0;
  }
  __syncthreads();
  // Gauss-Jordan with partial pivoting (32x64)
  for (int k = 0; k < 32; ++k) {
    if (tid == 0) {
      int p = k; double best = fabs(aug[k][k]);
      for (int r = k+1; r < 32; ++r) { double v = fabs(aug[r][k]); if (v > best) { best = v; p = r; } }
      sPiv = p;
    }
    __syncthreads();
    int p = sPiv;
    if (p != k) for (int c = tid; c < 64; c += 256) { double t1 = aug[k][c]; aug[k][c] = aug[p][c]; aug[p][c] = t1; }
    __syncthreads();
    double pinv = 1.0 / aug[k][k];
    __syncthreads();
    for (int c = tid; c < 64; c += 256) aug[k][c] *= pinv;
    __syncthreads();
    if (tid < 32) sFac[tid] = aug[tid][k];
    __syncthreads();
    for (int idx = tid; idx < 2048; idx += 256) {
      int r = idx >> 6, c = idx & 63;
      if (r != k) aug[r][c] -= sFac[r] * aug[k][c];
    }
    __syncthreads();
  }
  double* Rinv = wsd + OFF_RINV;
  for (int idx = tid; idx < 1024; idx += 256) Rinv[idx] = aug[idx >> 5][32 + (idx & 31)];

  // vec_r rows: [C2_cal^T (64) ; D21_cal^T (32) ; B2 (64)], M = I - eps*D22^T
  double* vr = wsd + OFF_VR;
  for (int idx = tid; idx < 64*32; idx += 256) {        // C2_cal^T: vr[p][k] = C2cal[k][p]
    int p = idx >> 5, k = idx & 31;
    double q = 0.0;
    for (int m = 0; m < 32; ++m) q += D22d[m*32+k] * (double)C2[m*64+p];
    vr[p*32+k] = (double)C2[k*64+p] - EPS_Q * q;
  }
  for (int idx = tid; idx < 32*32; idx += 256) {        // D21_cal^T
    int p = idx >> 5, k = idx & 31;
    double q = 0.0;
    for (int m = 0; m < 32; ++m) q += D22d[m*32+k] * (double)D21[m*32+p];
    vr[(64+p)*32+k] = (double)D21[k*32+p] - EPS_Q * q - (double)D12[p*32+k];
  }
  for (int idx = tid; idx < 64*32; idx += 256) {        // B2
    int p = idx >> 5, k = idx & 31;
    vr[(96+p)*32+k] = (double)B2[p*32+k];
  }
  __syncthreads();
  // T1 = vec_r @ Rinv  (160x32)
  double* T1 = wsd + OFF_T1;
  for (int idx = tid; idx < 160*32; idx += 256) {
    int p = idx >> 5, k2 = idx & 31;
    double s = 0.0;
    for (int k = 0; k < 32; ++k) s += vr[p*32+k] * Rinv[k*32+k2];
    T1[idx] = s;
  }
}

// ================= prep 2: H = X^T X + tol I + psi_r + eps*vq vq^T =================
__global__ __launch_bounds__(256, 1) void prep2(
    const float* __restrict__ X, const float* __restrict__ C2,
    const float* __restrict__ D21, double* __restrict__ wsd)
{
  const double* vr = wsd + OFF_VR;
  const double* T1 = wsd + OFF_T1;
  double* H = wsd + OFF_H;
  int bi = blockIdx.x / 10, bj = blockIdx.x % 10;
  int i = bi*16 + (threadIdx.x >> 4);
  int j = bj*16 + (threadIdx.x & 15);
  double s = (i == j) ? TOLC : 0.0;
  for (int k = 0; k < 160; ++k) s += (double)X[k*160+i] * (double)X[k*160+j];
  double pr = 0.0;
  for (int k = 0; k < 32; ++k) pr += T1[i*32+k] * vr[j*32+k];
  s += pr;
  if (i < 96 && j < 96) {
    double vq = 0.0;
    for (int k = 0; k < 32; ++k) {
      double a = (i < 64) ? (double)C2[k*64+i] : (double)D21[k*32+(i-64)];
      double b = (j < 64) ? (double)C2[k*64+j] : (double)D21[k*32+(j-64)];
      vq += a*b;
    }
    s += EPS_Q * vq;   // H - psi_q, psi_q = -eps * vq vq^T
  }
  H[i*160+j] = s;
}

// ================= prep 3: E^-1 (GJ fp32 + 2x fp64 Newton), weight blob =================
__global__ __launch_bounds__(256, 1) void prep3(
    const float* __restrict__ Y, const float* __restrict__ B2,
    const float* __restrict__ C2, const float* __restrict__ D12,
    const float* __restrict__ D21, double* __restrict__ wsd)
{
  __shared__ float aug[64][130];
  __shared__ float sFac[64];
  __shared__ int sPiv;
  const int tid = threadIdx.x;
  double* H   = wsd + OFF_H;
  double* Ed  = wsd + OFF_E;
  double* Ei  = wsd + OFF_EI;
  double* Tm  = wsd + OFF_TMP;
  double* Tm2 = wsd + OFF_TMP2;
  double* D22d = wsd + OFF_D22;
  float* fb = (float*)(wsd + D_END);

  // E = 0.5*(H11 + H33 + Y - Y^T)
  for (int idx = tid; idx < 4096; idx += 256) {
    int i = idx >> 6, j = idx & 63;
    double e = 0.5*(H[i*160+j] + H[(96+i)*160+(96+j)] + (double)Y[i*64+j] - (double)Y[j*64+i]);
    Ed[idx] = e;
    aug[i][j] = (float)e;
    aug[i][64+j] = (i == j) ? 1.f : 0.f;
  }
  __syncthreads();
  for (int k = 0; k < 64; ++k) {
    if (tid == 0) {
      int p = k; float best = fabsf(aug[k][k]);
      for (int r = k+1; r < 64; ++r) { float v = fabsf(aug[r][k]); if (v > best) { best = v; p = r; } }
      sPiv = p;
    }
    __syncthreads();
    int p = sPiv;
    if (p != k) for (int c = tid; c < 128; c += 256) { float t1 = aug[k][c]; aug[k][c] = aug[p][c]; aug[p][c] = t1; }
    __syncthreads();
    float pinv = 1.0f / aug[k][k];
    __syncthreads();
    for (int c = tid; c < 128; c += 256) aug[k][c] *= pinv;
    __syncthreads();
    if (tid < 64) sFac[tid] = aug[tid][k];
    __syncthreads();
    for (int idx = tid; idx < 64*128; idx += 256) {
      int r = idx >> 7, c = idx & 127;
      if (r != k) aug[r][c] -= sFac[r] * aug[k][c];
    }
    __syncthreads();
  }
  for (int idx = tid; idx < 4096; idx += 256) Ei[idx] = (double)aug[idx >> 6][64 + (idx & 63)];
  __syncthreads();
  // Newton refinement x2: Ei <- Ei (2I - Ed Ei)
  for (int it = 0; it < 2; ++it) {
    for (int idx = tid; idx < 4096; idx += 256) {
      int i = idx >> 6, j = idx & 63;
      double s = (i == j) ? 2.0 : 0.0;
      for (int k = 0; k < 64; ++k) s -= Ed[i*64+k] * Ei[k*64+j];
      Tm[idx] = s;
    }
    __syncthreads();
    for (int idx = tid; idx < 4096; idx += 256) {
      int i = idx >> 6, j = idx & 63;
      double s = 0.0;
      for (int k = 0; k < 64; ++k) s += Ei[i*64+k] * Tm[k*64+j];
      Tm2[idx] = s;
    }
    __syncthreads();
    for (int idx = tid; idx < 4096; idx += 256) Ei[idx] = Tm2[idx];
    __syncthreads();
  }
  // Wx = [A1 | A2 | A3] = Ei @ [Fm | B1 | B2],  Fm=H31, B1=H32
  for (int idx = tid; idx < 64*132; idx += 256) {
    int r = idx / 132, j = idx % 132;
    double s = 0.0;
    if (j < 64)       { for (int k = 0; k < 64; ++k) s += Ei[r*64+k] * H[(96+k)*160 + j]; }
    else if (j < 96)  { int jj = j-64; for (int k = 0; k < 64; ++k) s += Ei[r*64+k] * H[(96+k)*160 + 64 + jj]; }
    else if (j < 128) { int jj = j-96; for (int k = 0; k < 64; ++k) s += Ei[r*64+k] * (double)B2[k*32+jj]; }
    fb[F_WX + idx] = (float)s;
  }
  // Wy = [C2 | D21 | D22]
  for (int idx = tid; idx < 32*132; idx += 256) {
    int r = idx / 132, j = idx % 132;
    float v = 0.f;
    if (j < 64)       v = C2[r*64+j];
    else if (j < 96)  v = D21[r*32 + (j-64)];
    else if (j < 128) v = (float)D22d[r*32 + (j-96)];
    fb[F_WY + idx] = v;
  }
  // D11' (strict lower, scaled by 1/Lam_i) ; Lam_i = 0.5*H22[i][i]
  for (int idx = tid; idx < 1024; idx += 256) {
    int i = idx >> 5, j = idx & 31;
    double li = 2.0 / H[(64+i)*160 + 64+i];
    fb[F_D11 + idx] = (j < i) ? (float)(-H[(64+i)*160 + 64+j] * li) : 0.f;
  }
  // Wa = [C1 | D12] * (1/Lam_s), C1 = -H21
  for (int idx = tid; idx < 32*96; idx += 256) {
    int r = idx / 96, j = idx % 96;
    double li = 2.0 / H[(64+r)*160 + 64+r];
    double v = (j < 64) ? (-H[(64+r)*160 + j] * li) : ((double)D12[r*32 + (j-64)] * li);
    fb[F_WA + idx] = (float)v;
  }
}

// ================= main recurrence =================
__device__ __forceinline__ float frcp(float x) {
#if __has_builtin(__builtin_amdgcn_rcpf)
  return __builtin_amdgcn_rcpf(x);
#else
  return 1.0f / x;
#endif
}
__device__ __forceinline__ float ftanh(float x) {
  float xc = fminf(fmaxf(x, -15.f), 15.f);
  float E = __builtin_exp2f(xc * 2.8853900817779268f);  // e^{2x}
  return 1.f - 2.f * frcp(E + 1.f);
}
#define DOT4(m, v) ((m).x*(v).x + (m).y*(v).y + (m).z*(v).z + (m).w*(v).w)

__global__ __launch_bounds__(256, 1) void ren_main(
    const float* __restrict__ u_in, const float* __restrict__ x0,
    const double* __restrict__ wsd, float* __restrict__ out)
{
  __shared__ __align__(16) float sM[13696];     // Wx[64][132] | Wy[32][132] | D11[32][32]
  __shared__ __align__(16) float sX[2][8][68];  // ping-pong state
  __shared__ __align__(16) float sU[8][32];
  __shared__ __align__(16) float sA[8][32];
  const float* fb = (const float*)(wsd + D_END);
  const int tid = threadIdx.x;
  for (int i = tid; i < F_LDS_CNT; i += 256) sM[i] = fb[i];
  const int e = tid >> 5, s = tid & 31;
  const int b = blockIdx.x * 8 + e;
  for (int i = tid; i < 512; i += 256) {
    int el = i >> 6, c = i & 63;
    sX[0][el][c] = x0[(blockIdx.x*8 + el)*64 + c];
  }
  const float4* Wx4 = (const float4*)sM;            // row stride 33 f4
  const float4* Wy4 = (const float4*)(sM + 8448);   // row stride 33 f4
  const float4* D114 = (const float4*)(sM + 12672); // row stride 8 f4
  const float4* Wa4 = (const float4*)(fb + F_WA);   // global, row stride 24 f4
  const float* uptr = u_in + (size_t)b * 8192;
  float* optr = out + (size_t)b * 8192;
  float w[32];
  float ucur = uptr[s];  // prefetch t=0

  for (int t = 0; t < 256; ++t) {
    sU[e][s] = ucur;
    int tn = (t < 255) ? (t + 1) : 255;
    float unext = uptr[tn*32 + s];                  // prefetch next step
    __syncthreads();                                 // B1

    float4 xv[16], uv[8];
    const float4* xp = (const float4*)sX[t & 1][e];
    #pragma unroll
    for (int j = 0; j < 16; ++j) xv[j] = xp[j];
    const float4* up = (const float4*)sU[e];
    #pragma unroll
    for (int j = 0; j < 8; ++j) uv[j] = up[j];

    // a_s = (C1 x + D12 u)_s / Lam_s
    float acc = 0.f;
    #pragma unroll
    for (int j = 0; j < 16; ++j) acc += DOT4(Wa4[s*24 + j], xv[j]);
    #pragma unroll
    for (int j = 0; j < 8; ++j) acc += DOT4(Wa4[s*24 + 16 + j], uv[j]);
    sA[e][s] = acc;
    __syncthreads();                                 // B2

    // serial tanh forward-substitution (redundant per slice; free within a wave)
    #pragma unroll
    for (int j = 0; j < 32; ++j) w[j] = 0.f;
    #pragma unroll
    for (int i = 0; i < 32; ++i) {
      float v = sA[e][i];
      const int nch = (i + 3) >> 2;
      #pragma unroll
      for (int jj = 0; jj < nch; ++jj) {
        float4 d = D114[i*8 + jj];
        v += d.x*w[4*jj] + d.y*w[4*jj+1] + d.z*w[4*jj+2] + d.w*w[4*jj+3];
      }
      w[i] = ftanh(v);
    }

    // x_new rows s and s+32
    float a0 = 0.f, a1 = 0.f;
    #pragma unroll
    for (int j = 0; j < 16; ++j) { a0 += DOT4(Wx4[s*33 + j], xv[j]); a1 += DOT4(Wx4[(s+32)*33 + j], xv[j]); }
    #pragma unroll
    for (int j = 0; j < 8; ++j) {
      float4 m0 = Wx4[s*33 + 16 + j], m1 = Wx4[(s+32)*33 + 16 + j];
      float w0 = w[4*j], w1 = w[4*j+1], w2 = w[4*j+2], w3 = w[4*j+3];
      a0 += m0.x*w0 + m0.y*w1 + m0.z*w2 + m0.w*w3;
      a1 += m1.x*w0 + m1.y*w1 + m1.z*w2 + m1.w*w3;
    }
    #pragma unroll
    for (int j = 0; j < 8; ++j) { a0 += DOT4(Wx4[s*33 + 24 + j], uv[j]); a1 += DOT4(Wx4[(s+32)*33 + 24 + j], uv[j]); }
    const int nb = ((t & 1) ^ 1);
    sX[nb][e][s] = a0;
    sX[nb][e][s + 32] = a1;
    __syncthreads();                                 // B3

    // y row s
    const float4* np_ = (const float4*)sX[nb][e];
    #pragma unroll
    for (int j = 0; j < 16; ++j) xv[j] = np_[j];
    float ya = 0.f;
    #pragma unroll
    for (int j = 0; j < 16; ++j) ya += DOT4(Wy4[s*33 + j], xv[j]);
    #pragma unroll
    for (int j = 0; j < 8; ++j) {
      float4 m = Wy4[s*33 + 16 + j];
      ya += m.x*w[4*j] + m.y*w[4*j+1] + m.z*w[4*j+2] + m.w*w[4*j+3];
    }
    #pragma unroll
    for (int j = 0; j < 8; ++j) ya += DOT4(Wy4[s*33 + 24 + j], uv[j]);
    optr[t*32 + s] = ya;
    ucur = unext;
  }
}

// ================= launch =================
extern "C" void kernel_launch(void* const* d_in, const int* in_sizes, int n_in,
                              void* d_out, int out_size, void* d_ws, size_t ws_size,
                              hipStream_t stream)
{
  const float* u_in = (const float*)d_in[0];
  const float* x0   = (const float*)d_in[1];
  const float* X    = (const float*)d_in[2];
  const float* Y    = (const float*)d_in[3];
  const float* B2   = (const float*)d_in[4];
  const float* C2   = (const float*)d_in[5];
  const float* D12  = (const float*)d_in[6];
  const float* L    = (const float*)d_in[7];   // D22_L
  const float* U    = (const float*)d_in[8];   // D22_U
  const float* D21  = (const float*)d_in[9];
  const float* gam  = (const float*)d_in[10];
  double* wsd = (double*)d_ws;
  float* out = (float*)d_out;

  hipLaunchKernelGGL(prep1, dim3(1), dim3(256), 0, stream, B2, C2, D12, L, U, D21, gam, wsd);
  hipLaunchKernelGGL(prep2, dim3(100), dim3(256), 0, stream, X, C2, D21, wsd);
  hipLaunchKernelGGL(prep3, dim3(1), dim3(256), 0, stream, Y, B2, C2, D12, D21, wsd);
  hipLaunchKernelGGL(ren_main, dim3(256), dim3(256), 0, stream, u_in, x0, wsd, out);
}